// Round 2
// baseline (535.005 us; speedup 1.0000x reference)
//
#include <hip/hip_runtime.h>

// Problem constants (from reference): N=100000 nodes, S=50 relations,
// B=30 bases, OUT=16, E=20000 edges/relation. S,B,OUT hardcoded (compile-time
// magic-div for /50); N and E derived from in_sizes.
constexpr int S_REL = 50;
constexpr int B_BASES = 30;
constexpr int OUT_DIM = 16;

__global__ __launch_bounds__(256) void zero_out_kernel(float4* __restrict__ p, int n4) {
    int i = blockIdx.x * blockDim.x + threadIdx.x;
    int stride = gridDim.x * blockDim.x;
    for (; i < n4; i += stride) p[i] = make_float4(0.f, 0.f, 0.f, 0.f);
}

__global__ __launch_bounds__(256) void relu_inplace_kernel(float4* __restrict__ p, int n4) {
    int i = blockIdx.x * blockDim.x + threadIdx.x;
    int stride = gridDim.x * blockDim.x;
    for (; i < n4; i += stride) {
        float4 v = p[i];
        v.x = fmaxf(v.x, 0.f);
        v.y = fmaxf(v.y, 0.f);
        v.z = fmaxf(v.z, 0.f);
        v.w = fmaxf(v.w, 0.f);
        p[i] = v;
    }
}

// 4 lanes per edge; lane handles 4 consecutive output columns (float4).
// msg[o] = val * sum_b Wcomp[rel', b] * W[(b*N + node')*16 + o]
// where k = r*N + dst, node' = k/50, rel' = k%50 (the reference's
// node-major-reshape vs relation-major-gather index quirk).
__global__ __launch_bounds__(256) void rgcn_edge_kernel(
    const int* __restrict__ src, const int* __restrict__ dst,
    const float* __restrict__ vals, const float* __restrict__ W,
    const float* __restrict__ Wcomp, float* __restrict__ out,
    int N, int E, int nEdges) {
    __shared__ float wc[S_REL * B_BASES];  // 1500 floats = 6 KB
    for (int i = threadIdx.x; i < S_REL * B_BASES; i += blockDim.x)
        wc[i] = Wcomp[i];
    __syncthreads();

    int t = blockIdx.x * blockDim.x + threadIdx.x;
    int edge = t >> 2;
    int o4 = (t & 3) * 4;   // output column group: 0,4,8,12
    if (edge >= nEdges) return;

    int r = edge / E;                 // relation index (edges are [S,E] flat)
    int d = dst[edge];
    int s = src[edge];
    float v = vals[edge];

    int k = r * N + d;                // < 5e6, fits int32
    int node = k / S_REL;             // compile-time const divisor -> magic mul
    int rel = k - node * S_REL;

    const float* wp = W + (size_t)node * OUT_DIM + o4;
    const size_t bstride = (size_t)N * OUT_DIM;  // floats between bases
    const float* wcr = wc + rel * B_BASES;

    // Pull the 30 basis coefficients for this edge's rel' into registers.
    float c[B_BASES];
#pragma unroll
    for (int b = 0; b < B_BASES; ++b) c[b] = wcr[b];

    float4 acc = make_float4(0.f, 0.f, 0.f, 0.f);
#pragma unroll
    for (int b = 0; b < B_BASES; ++b) {
        float4 w4 = *reinterpret_cast<const float4*>(wp + (size_t)b * bstride);
        acc.x = fmaf(c[b], w4.x, acc.x);
        acc.y = fmaf(c[b], w4.y, acc.y);
        acc.z = fmaf(c[b], w4.z, acc.z);
        acc.w = fmaf(c[b], w4.w, acc.w);
    }

    float* op = out + (size_t)s * OUT_DIM + o4;
    atomicAdd(op + 0, v * acc.x);
    atomicAdd(op + 1, v * acc.y);
    atomicAdd(op + 2, v * acc.z);
    atomicAdd(op + 3, v * acc.w);
}

extern "C" void kernel_launch(void* const* d_in, const int* in_sizes, int n_in,
                              void* d_out, int out_size, void* d_ws, size_t ws_size,
                              hipStream_t stream) {
    // setup_inputs order: features, src, dst, vals, W, W_comp
    const int* src = (const int*)d_in[1];
    const int* dst = (const int*)d_in[2];
    const float* vals = (const float*)d_in[3];
    const float* W = (const float*)d_in[4];
    const float* Wcomp = (const float*)d_in[5];
    float* out = (float*)d_out;

    const int N = in_sizes[0];            // features is (N,1)
    const int nEdges = in_sizes[1];       // S*E
    const int E = nEdges / S_REL;

    const int n4 = out_size / 4;          // N*OUT/4 float4s
    int zb = (n4 + 255) / 256;
    const int zblocks = zb < 2048 ? zb : 2048;
    zero_out_kernel<<<zblocks, 256, 0, stream>>>((float4*)out, n4);

    const long long threads = (long long)nEdges * 4;
    const int eblocks = (int)((threads + 255) / 256);
    rgcn_edge_kernel<<<eblocks, 256, 0, stream>>>(src, dst, vals, W, Wcomp, out,
                                                  N, E, nEdges);

    relu_inplace_kernel<<<zblocks, 256, 0, stream>>>((float4*)out, n4);
}

// Round 3
// 486.422 us; speedup vs baseline: 1.0999x; 1.0999x over previous
//
#include <hip/hip_runtime.h>

// Problem constants (from reference): N=100000 nodes, S=50 relations,
// B=30 bases, OUT=16, E=20000 edges/relation.
// Key index identity (N % S == 0): for edge (r, d):
//   k = r*N + d ; node' = k/50 = r*2000 + d/50 ; rel' = k%50 = d%50.
// Relation r's W working set = rows node' in [r*2000, r*2000+2000) x 30 bases
// = 3.84 MB -> fits one XCD's 4 MiB L2. Hence XCD-relation affinity below.
constexpr int S_REL = 50;
constexpr int B_BASES = 30;
constexpr int OUT_DIM = 16;
constexpr int NXCD = 8;
constexpr int EDGES_PER_BLOCK = 64;   // 256 threads, 4 lanes/edge

__global__ __launch_bounds__(256) void relu_inplace_kernel(float4* __restrict__ p, int n4) {
    int i = blockIdx.x * blockDim.x + threadIdx.x;
    int stride = gridDim.x * blockDim.x;
    for (; i < n4; i += stride) {
        float4 v = p[i];
        v.x = fmaxf(v.x, 0.f);
        v.y = fmaxf(v.y, 0.f);
        v.z = fmaxf(v.z, 0.f);
        v.w = fmaxf(v.w, 0.f);
        p[i] = v;
    }
}

// 4 lanes per edge; lane handles 4 consecutive output columns (float4).
// msg[o] = val * sum_b Wcomp[rel', b] * W[(b*N + node')*16 + o]
// XCD affinity: XCD x = bid % 8 gets contiguous chunk range [x*P, x*P+P)
// of the relation-major edge array, so each L2 streams adjacent relation
// slabs one at a time instead of thrashing all 50.
__global__ __launch_bounds__(256) void rgcn_edge_kernel(
    const int* __restrict__ src, const int* __restrict__ dst,
    const float* __restrict__ vals, const float* __restrict__ W,
    const float* __restrict__ Wcomp, float* __restrict__ out,
    int N, int E, int nEdges, int chunksPerXcd, int nChunks) {
    __shared__ float wc[S_REL * B_BASES];  // 1500 floats = 6 KB
    for (int i = threadIdx.x; i < S_REL * B_BASES; i += blockDim.x)
        wc[i] = Wcomp[i];
    __syncthreads();

    const int x = blockIdx.x % NXCD;          // physical XCD (round-robin dispatch)
    const int j = blockIdx.x / NXCD;          // sequence within this XCD
    const int chunk = x * chunksPerXcd + j;   // contiguous edge-chunk range per XCD
    if (chunk >= nChunks) return;

    const int edge = chunk * EDGES_PER_BLOCK + (threadIdx.x >> 2);
    const int o4 = (threadIdx.x & 3) * 4;     // output column group: 0,4,8,12
    if (edge >= nEdges) return;

    const int r = edge / E;                   // relation (edges are [S,E] flat)
    const int d = dst[edge];
    const int s = src[edge];
    const float v = vals[edge];

    const int k = r * N + d;                  // < 5e6, fits int32
    const int node = k / S_REL;               // const divisor -> magic mul
    const int rel = k - node * S_REL;

    const float* wp = W + (size_t)node * OUT_DIM + o4;
    const size_t bstride = (size_t)N * OUT_DIM;
    const float* wcr = wc + rel * B_BASES;

    float c[B_BASES];
#pragma unroll
    for (int b = 0; b < B_BASES; ++b) c[b] = wcr[b];

    float4 acc = make_float4(0.f, 0.f, 0.f, 0.f);
#pragma unroll
    for (int b = 0; b < B_BASES; ++b) {
        float4 w4 = *reinterpret_cast<const float4*>(wp + (size_t)b * bstride);
        acc.x = fmaf(c[b], w4.x, acc.x);
        acc.y = fmaf(c[b], w4.y, acc.y);
        acc.z = fmaf(c[b], w4.z, acc.z);
        acc.w = fmaf(c[b], w4.w, acc.w);
    }

    float* op = out + (size_t)s * OUT_DIM + o4;
    atomicAdd(op + 0, v * acc.x);
    atomicAdd(op + 1, v * acc.y);
    atomicAdd(op + 2, v * acc.z);
    atomicAdd(op + 3, v * acc.w);
}

extern "C" void kernel_launch(void* const* d_in, const int* in_sizes, int n_in,
                              void* d_out, int out_size, void* d_ws, size_t ws_size,
                              hipStream_t stream) {
    // setup_inputs order: features, src, dst, vals, W, W_comp
    const int* src = (const int*)d_in[1];
    const int* dst = (const int*)d_in[2];
    const float* vals = (const float*)d_in[3];
    const float* W = (const float*)d_in[4];
    const float* Wcomp = (const float*)d_in[5];
    float* out = (float*)d_out;

    const int N = in_sizes[0];            // features is (N,1)
    const int nEdges = in_sizes[1];       // S*E
    const int E = nEdges / S_REL;

    // zero-init accumulator (float 0.0f == all-zero bytes); memset node is
    // graph-capture legal and cheaper than a kernel launch.
    hipMemsetAsync(d_out, 0, (size_t)out_size * sizeof(float), stream);

    const int nChunks = (nEdges + EDGES_PER_BLOCK - 1) / EDGES_PER_BLOCK;
    const int chunksPerXcd = (nChunks + NXCD - 1) / NXCD;
    const int eblocks = chunksPerXcd * NXCD;
    rgcn_edge_kernel<<<eblocks, 256, 0, stream>>>(src, dst, vals, W, Wcomp, out,
                                                  N, E, nEdges, chunksPerXcd, nChunks);

    const int n4 = out_size / 4;          // N*OUT/4 float4s
    int zb = (n4 + 255) / 256;
    const int rblocks = zb < 2048 ? zb : 2048;
    relu_inplace_kernel<<<rblocks, 256, 0, stream>>>((float4*)out, n4);
}